// Round 1
// baseline (1438.134 us; speedup 1.0000x reference)
//
#include <hip/hip_runtime.h>
#include <math.h>

#define D_FEAT 128

// Kernel A: per-row hyperbolic scale = artanh(clip(||x||)) / max(||x||, 1e-15)
// One 64-lane wave per row; each lane loads float2 (2 features).
__global__ void hyp_scale_kernel(const float* __restrict__ x,
                                 float* __restrict__ scale,
                                 int n_nodes) {
    const int lane = threadIdx.x & 63;
    const int wave = threadIdx.x >> 6;
    const int row = blockIdx.x * (blockDim.x >> 6) + wave;
    if (row >= n_nodes) return;

    const float2* xr = (const float2*)(x + (size_t)row * D_FEAT);
    float2 v = xr[lane];
    float ss = v.x * v.x + v.y * v.y;

    // wave-64 butterfly reduction
    #pragma unroll
    for (int off = 32; off > 0; off >>= 1)
        ss += __shfl_xor(ss, off, 64);

    if (lane == 0) {
        float norm = sqrtf(ss);
        float nc = fmaxf(norm, 1e-15f);
        // clip to (-1+eps, 1-eps); in fp32 1-1e-15 rounds to 1, matching the
        // fp32 reference. norms here are ~1e-2 so this is far from the clamp.
        float u = fminf(nc, 1.0f - 1e-15f);
        // artanh(u) = 0.5*(log1p(u) - log1p(-u)) — accurate at small u
        float at = 0.5f * (log1pf(u) - log1pf(-u));
        scale[row] = at / nc;
    }
}

// Kernel B: edge-parallel scatter-add.
// 32 threads per edge; thread t handles features [4t, 4t+4).
__global__ void hyp_agg_kernel(const float* __restrict__ x,
                               const float* __restrict__ scale,
                               const int* __restrict__ rows,
                               const int* __restrict__ cols,
                               const float* __restrict__ vals,
                               float* __restrict__ out,
                               int n_edges) {
    int gid = blockIdx.x * blockDim.x + threadIdx.x;
    int e = gid >> 5;
    int t = gid & 31;
    if (e >= n_edges) return;

    int r = rows[e];
    int c = cols[e];
    float w = vals[e] * scale[c];

    const float4* xc = (const float4*)(x + (size_t)c * D_FEAT);
    float4 xv = xc[t];

    float* o = out + (size_t)r * D_FEAT + t * 4;
    atomicAdd(o + 0, w * xv.x);
    atomicAdd(o + 1, w * xv.y);
    atomicAdd(o + 2, w * xv.z);
    atomicAdd(o + 3, w * xv.w);
}

extern "C" void kernel_launch(void* const* d_in, const int* in_sizes, int n_in,
                              void* d_out, int out_size, void* d_ws, size_t ws_size,
                              hipStream_t stream) {
    const float* x      = (const float*)d_in[0];
    const int*   rows   = (const int*)d_in[1];
    const int*   cols   = (const int*)d_in[2];
    const float* vals   = (const float*)d_in[3];
    float* out = (float*)d_out;

    const int n_nodes = in_sizes[0] / D_FEAT;
    const int n_edges = in_sizes[1];

    float* scale = (float*)d_ws;  // n_nodes floats (200 KB)

    // Kernel A: 4 waves (4 rows) per 256-thread block
    {
        int rows_per_block = 256 / 64;
        int grid = (n_nodes + rows_per_block - 1) / rows_per_block;
        hyp_scale_kernel<<<grid, 256, 0, stream>>>(x, scale, n_nodes);
    }

    // Zero the output (harness poisons it with 0xAA before every launch)
    hipMemsetAsync(d_out, 0, (size_t)out_size * sizeof(float), stream);

    // Kernel B: 32 threads/edge
    {
        long long total = (long long)n_edges * 32;
        int grid = (int)((total + 255) / 256);
        hyp_agg_kernel<<<grid, 256, 0, stream>>>(x, scale, rows, cols, vals,
                                                 out, n_edges);
    }
}

// Round 2
// 387.653 us; speedup vs baseline: 3.7099x; 3.7099x over previous
//
#include <hip/hip_runtime.h>
#include <math.h>

#define D_FEAT 128
#define SCAN_THREADS 1024

// ---------------- workspace layout (element offsets, 4B each) ----------------
// scale      [50048)          per-node logmap0 scale
// counts     [50048, 100096)  per-row edge counts
// offsets    [100096, 150208) exclusive-scan offsets (n+1 used)
// cursor     [150208, 200256) scatter cursors (copy of offsets)
// col_sorted [200256, 1000256)
// w_sorted   [1000256, 1800256)
// total ~7.2 MB

// Kernel A: per-row hyperbolic scale = artanh(clip(||x||)) / max(||x||,1e-15)
__global__ void hyp_scale_kernel(const float* __restrict__ x,
                                 float* __restrict__ scale,
                                 int n_nodes) {
    const int lane = threadIdx.x & 63;
    const int wave = threadIdx.x >> 6;
    const int row = blockIdx.x * (blockDim.x >> 6) + wave;
    if (row >= n_nodes) return;

    const float2* xr = (const float2*)(x + (size_t)row * D_FEAT);
    float2 v = xr[lane];
    float ss = v.x * v.x + v.y * v.y;
    #pragma unroll
    for (int off = 32; off > 0; off >>= 1)
        ss += __shfl_xor(ss, off, 64);

    if (lane == 0) {
        float norm = sqrtf(ss);
        float nc = fmaxf(norm, 1e-15f);
        float u = fminf(nc, 1.0f - 1e-15f);
        float at = 0.5f * (log1pf(u) - log1pf(-u));
        scale[row] = at / nc;
    }
}

// Kernel B: histogram of destination rows (int atomics)
__global__ void hist_kernel(const int* __restrict__ rows,
                            int* __restrict__ counts, int n_edges) {
    int e = blockIdx.x * blockDim.x + threadIdx.x;
    if (e < n_edges) atomicAdd(&counts[rows[e]], 1);
}

// Kernel C: single-block exclusive scan. Each thread owns a contiguous run
// of ceil(n/1024) elements; local sum -> one LDS block scan -> local rewalk.
__global__ void scan_kernel(const int* __restrict__ counts,
                            int* __restrict__ offsets,
                            int* __restrict__ cursor, int n) {
    __shared__ int smem[SCAN_THREADS];
    const int per = (n + SCAN_THREADS - 1) / SCAN_THREADS;  // 49
    const int tid = threadIdx.x;
    const int lo = tid * per;
    const int hi = min(lo + per, n);

    int s = 0;
    for (int i = lo; i < hi; ++i) s += counts[i];
    smem[tid] = s;
    __syncthreads();
    // inclusive scan of thread sums
    for (int off = 1; off < SCAN_THREADS; off <<= 1) {
        int t = (tid >= off) ? smem[tid - off] : 0;
        __syncthreads();
        smem[tid] += t;
        __syncthreads();
    }
    int run = smem[tid] - s;  // exclusive prefix of this thread's run
    for (int i = lo; i < hi; ++i) {
        offsets[i] = run;
        cursor[i] = run;
        run += counts[i];
    }
    if (tid == SCAN_THREADS - 1) offsets[n] = smem[SCAN_THREADS - 1];
}

// Kernel D: scatter edges into CSR buckets, pre-multiplying val*scale[col]
__global__ void scatter_kernel(const int* __restrict__ rows,
                               const int* __restrict__ cols,
                               const float* __restrict__ vals,
                               const float* __restrict__ scale,
                               int* __restrict__ cursor,
                               int* __restrict__ col_sorted,
                               float* __restrict__ w_sorted, int n_edges) {
    int e = blockIdx.x * blockDim.x + threadIdx.x;
    if (e >= n_edges) return;
    int r = rows[e];
    int c = cols[e];
    int slot = atomicAdd(&cursor[r], 1);
    col_sorted[slot] = c;
    w_sorted[slot] = vals[e] * scale[c];
}

// Kernel E: one wave per output row. Lane l accumulates features [2l, 2l+2).
__global__ void gather_kernel(const float* __restrict__ x,
                              const int* __restrict__ offsets,
                              const int* __restrict__ col_sorted,
                              const float* __restrict__ w_sorted,
                              float* __restrict__ out, int n_nodes) {
    const int lane = threadIdx.x & 63;
    const int wave = threadIdx.x >> 6;
    const int row = blockIdx.x * (blockDim.x >> 6) + wave;
    if (row >= n_nodes) return;

    const int start = offsets[row];
    const int end = offsets[row + 1];

    float2 acc = {0.0f, 0.0f};
    for (int j = start; j < end; ++j) {
        int c = col_sorted[j];       // wave-uniform (broadcast load)
        float w = w_sorted[j];
        const float2* xr = (const float2*)(x + (size_t)c * D_FEAT);
        float2 v = xr[lane];
        acc.x += w * v.x;
        acc.y += w * v.y;
    }
    float2* o = (float2*)(out + (size_t)row * D_FEAT);
    o[lane] = acc;
}

extern "C" void kernel_launch(void* const* d_in, const int* in_sizes, int n_in,
                              void* d_out, int out_size, void* d_ws, size_t ws_size,
                              hipStream_t stream) {
    const float* x    = (const float*)d_in[0];
    const int*   rows = (const int*)d_in[1];
    const int*   cols = (const int*)d_in[2];
    const float* vals = (const float*)d_in[3];
    float* out = (float*)d_out;

    const int n_nodes = in_sizes[0] / D_FEAT;  // 50000
    const int n_edges = in_sizes[1];           // 800000

    float* ws = (float*)d_ws;
    float* scale      = ws;                       // 50048
    int*   counts     = (int*)(ws + 50048);       // 50048
    int*   offsets    = (int*)(ws + 100096);      // 50112 (n+1 used)
    int*   cursor     = (int*)(ws + 150208);      // 50048
    int*   col_sorted = (int*)(ws + 200256);      // 800000
    float* w_sorted   = ws + 1000256;             // 800000

    // A: per-node scale (4 rows per 256-thread block)
    {
        int grid = (n_nodes + 3) / 4;
        hyp_scale_kernel<<<grid, 256, 0, stream>>>(x, scale, n_nodes);
    }
    // zero the histogram (ws is poisoned each launch)
    hipMemsetAsync(counts, 0, (size_t)n_nodes * sizeof(int), stream);
    // B: histogram
    {
        int grid = (n_edges + 255) / 256;
        hist_kernel<<<grid, 256, 0, stream>>>(rows, counts, n_edges);
    }
    // C: scan (single block)
    scan_kernel<<<1, SCAN_THREADS, 0, stream>>>(counts, offsets, cursor, n_nodes);
    // D: scatter into CSR
    {
        int grid = (n_edges + 255) / 256;
        scatter_kernel<<<grid, 256, 0, stream>>>(rows, cols, vals, scale, cursor,
                                                 col_sorted, w_sorted, n_edges);
    }
    // E: gather-reduce, one wave per row
    {
        int grid = (n_nodes + 3) / 4;
        gather_kernel<<<grid, 256, 0, stream>>>(x, offsets, col_sorted, w_sorted,
                                                out, n_nodes);
    }
}

// Round 3
// 285.265 us; speedup vs baseline: 5.0414x; 1.3589x over previous
//
#include <hip/hip_runtime.h>
#include <math.h>

#define D_FEAT 128

// ---------------- workspace layout (element offsets, 4B each) ----------------
// scale      [0, 50048)
// counts     [50048, 100096)
// offsets    [100096, 150208)   (n+1 used)
// cursor     [150208, 200256)
// col_sorted [200256, 1000256)
// w_sorted   [1000256, 1800256)
// blocksums  [1800256, 1800320)  (49 used)
// blockoffs  [1800320, 1800384)
// total ~7.2 MB

// Kernel A: per-row hyperbolic scale = artanh(clip(||x||)) / max(||x||,1e-15)
__global__ void hyp_scale_kernel(const float* __restrict__ x,
                                 float* __restrict__ scale,
                                 int n_nodes) {
    const int lane = threadIdx.x & 63;
    const int wave = threadIdx.x >> 6;
    const int row = blockIdx.x * (blockDim.x >> 6) + wave;
    if (row >= n_nodes) return;

    const float2* xr = (const float2*)(x + (size_t)row * D_FEAT);
    float2 v = xr[lane];
    float ss = v.x * v.x + v.y * v.y;
    #pragma unroll
    for (int off = 32; off > 0; off >>= 1)
        ss += __shfl_xor(ss, off, 64);

    if (lane == 0) {
        float norm = sqrtf(ss);
        float nc = fmaxf(norm, 1e-15f);
        float u = fminf(nc, 1.0f - 1e-15f);
        float at = 0.5f * (log1pf(u) - log1pf(-u));
        scale[row] = at / nc;
    }
}

// Kernel B: histogram of destination rows (int atomics)
__global__ void hist_kernel(const int* __restrict__ rows,
                            int* __restrict__ counts, int n_edges) {
    int e = blockIdx.x * blockDim.x + threadIdx.x;
    if (e < n_edges) atomicAdd(&counts[rows[e]], 1);
}

// Kernel C1: per-block sums of counts (coalesced)
__global__ void scan_sum_kernel(const int* __restrict__ counts,
                                int* __restrict__ blocksums, int n) {
    __shared__ int smem[1024];
    int i = blockIdx.x * 1024 + threadIdx.x;
    smem[threadIdx.x] = (i < n) ? counts[i] : 0;
    __syncthreads();
    for (int off = 512; off > 0; off >>= 1) {
        if (threadIdx.x < off) smem[threadIdx.x] += smem[threadIdx.x + off];
        __syncthreads();
    }
    if (threadIdx.x == 0) blocksums[blockIdx.x] = smem[0];
}

// Kernel C2: one wave scans the block sums (nb <= 64); lane 63 writes total.
__global__ void scan_top_kernel(const int* __restrict__ blocksums,
                                int* __restrict__ blockoffs,
                                int* __restrict__ total_out, int nb) {
    int lane = threadIdx.x;
    int orig = (lane < nb) ? blocksums[lane] : 0;
    int v = orig;
    #pragma unroll
    for (int off = 1; off < 64; off <<= 1) {
        int t = __shfl_up(v, off, 64);
        if (lane >= off) v += t;
    }
    if (lane < nb) blockoffs[lane] = v - orig;
    if (lane == 63) total_out[0] = v;
}

// Kernel C3: block-local exclusive scan + block offset, coalesced writes.
__global__ void scan_apply_kernel(const int* __restrict__ counts,
                                  const int* __restrict__ blockoffs,
                                  int* __restrict__ offsets,
                                  int* __restrict__ cursor, int n) {
    __shared__ int smem[1024];
    int i = blockIdx.x * 1024 + threadIdx.x;
    int v = (i < n) ? counts[i] : 0;
    smem[threadIdx.x] = v;
    __syncthreads();
    for (int off = 1; off < 1024; off <<= 1) {
        int t = (threadIdx.x >= (unsigned)off) ? smem[threadIdx.x - off] : 0;
        __syncthreads();
        smem[threadIdx.x] += t;
        __syncthreads();
    }
    if (i < n) {
        int excl = smem[threadIdx.x] - v + blockoffs[blockIdx.x];
        offsets[i] = excl;
        cursor[i] = excl;
    }
}

// Kernel D: scatter edges into CSR buckets, pre-multiplying val*scale[col]
__global__ void scatter_kernel(const int* __restrict__ rows,
                               const int* __restrict__ cols,
                               const float* __restrict__ vals,
                               const float* __restrict__ scale,
                               int* __restrict__ cursor,
                               int* __restrict__ col_sorted,
                               float* __restrict__ w_sorted, int n_edges) {
    int e = blockIdx.x * blockDim.x + threadIdx.x;
    if (e >= n_edges) return;
    int r = rows[e];
    int c = cols[e];
    int slot = atomicAdd(&cursor[r], 1);
    col_sorted[slot] = c;
    w_sorted[slot] = vals[e] * scale[c];
}

// Kernel E: one wave per output row. Lane l accumulates features [2l, 2l+2).
__global__ void gather_kernel(const float* __restrict__ x,
                              const int* __restrict__ offsets,
                              const int* __restrict__ col_sorted,
                              const float* __restrict__ w_sorted,
                              float* __restrict__ out, int n_nodes) {
    const int lane = threadIdx.x & 63;
    const int wave = threadIdx.x >> 6;
    const int row = blockIdx.x * (blockDim.x >> 6) + wave;
    if (row >= n_nodes) return;

    const int start = offsets[row];
    const int end = offsets[row + 1];

    float2 acc = {0.0f, 0.0f};
    for (int j = start; j < end; ++j) {
        int c = col_sorted[j];       // wave-uniform (broadcast load)
        float w = w_sorted[j];
        const float2* xr = (const float2*)(x + (size_t)c * D_FEAT);
        float2 v = xr[lane];
        acc.x += w * v.x;
        acc.y += w * v.y;
    }
    float2* o = (float2*)(out + (size_t)row * D_FEAT);
    o[lane] = acc;
}

extern "C" void kernel_launch(void* const* d_in, const int* in_sizes, int n_in,
                              void* d_out, int out_size, void* d_ws, size_t ws_size,
                              hipStream_t stream) {
    const float* x    = (const float*)d_in[0];
    const int*   rows = (const int*)d_in[1];
    const int*   cols = (const int*)d_in[2];
    const float* vals = (const float*)d_in[3];
    float* out = (float*)d_out;

    const int n_nodes = in_sizes[0] / D_FEAT;  // 50000
    const int n_edges = in_sizes[1];           // 800000

    float* ws = (float*)d_ws;
    float* scale      = ws;                       // 50048
    int*   counts     = (int*)(ws + 50048);       // 50048
    int*   offsets    = (int*)(ws + 100096);      // 50112 (n+1 used)
    int*   cursor     = (int*)(ws + 150208);      // 50048
    int*   col_sorted = (int*)(ws + 200256);      // 800000
    float* w_sorted   = ws + 1000256;             // 800000
    int*   blocksums  = (int*)(ws + 1800256);     // 64
    int*   blockoffs  = (int*)(ws + 1800320);     // 64

    const int nb = (n_nodes + 1023) / 1024;       // 49

    // A: per-node scale (4 rows per 256-thread block)
    {
        int grid = (n_nodes + 3) / 4;
        hyp_scale_kernel<<<grid, 256, 0, stream>>>(x, scale, n_nodes);
    }
    // zero the histogram (ws is poisoned each launch)
    hipMemsetAsync(counts, 0, (size_t)n_nodes * sizeof(int), stream);
    // B: histogram
    {
        int grid = (n_edges + 255) / 256;
        hist_kernel<<<grid, 256, 0, stream>>>(rows, counts, n_edges);
    }
    // C: hierarchical exclusive scan
    scan_sum_kernel<<<nb, 1024, 0, stream>>>(counts, blocksums, n_nodes);
    scan_top_kernel<<<1, 64, 0, stream>>>(blocksums, blockoffs,
                                          offsets + n_nodes, nb);
    scan_apply_kernel<<<nb, 1024, 0, stream>>>(counts, blockoffs, offsets,
                                               cursor, n_nodes);
    // D: scatter into CSR
    {
        int grid = (n_edges + 255) / 256;
        scatter_kernel<<<grid, 256, 0, stream>>>(rows, cols, vals, scale, cursor,
                                                 col_sorted, w_sorted, n_edges);
    }
    // E: gather-reduce, one wave per row
    {
        int grid = (n_nodes + 3) / 4;
        gather_kernel<<<grid, 256, 0, stream>>>(x, offsets, col_sorted, w_sorted,
                                                out, n_nodes);
    }
}

// Round 4
// 266.742 us; speedup vs baseline: 5.3915x; 1.0694x over previous
//
#include <hip/hip_runtime.h>
#include <math.h>

#define D_FEAT 128

// ---------------- workspace layout ----------------
// xt       : bf16 pre-scaled features, 50000*128*2B = 12.8 MB
// counts   : int[50048]
// offsets  : int[50112] (n+1 used)
// cursor   : int[50048]
// packed   : int2[800000] {col, val_bits} = 6.4 MB
// blocksums/blockoffs: int[64] each
// total ~19.9 MB

static __device__ inline unsigned short f2bf(float f) {
    unsigned u = __float_as_uint(f);
    u += 0x7FFFu + ((u >> 16) & 1u);   // round-to-nearest-even
    return (unsigned short)(u >> 16);
}

// Kernel A: per-row logmap0 scale, fused with bf16 pre-scaled row write.
// One wave per row; lane l owns features [2l, 2l+1].
__global__ void hyp_scale_kernel(const float* __restrict__ x,
                                 unsigned short* __restrict__ xt,
                                 int n_nodes) {
    const int lane = threadIdx.x & 63;
    const int wave = threadIdx.x >> 6;
    const int row = blockIdx.x * (blockDim.x >> 6) + wave;
    if (row >= n_nodes) return;

    const float2* xr = (const float2*)(x + (size_t)row * D_FEAT);
    float2 v = xr[lane];
    float ss = v.x * v.x + v.y * v.y;
    #pragma unroll
    for (int off = 32; off > 0; off >>= 1)
        ss += __shfl_xor(ss, off, 64);
    // all lanes now hold the full sum

    float norm = sqrtf(ss);
    float nc = fmaxf(norm, 1e-15f);
    float u = fminf(nc, 1.0f - 1e-15f);
    float at = 0.5f * (log1pf(u) - log1pf(-u));
    float s = at / nc;

    ushort2 o;
    o.x = f2bf(v.x * s);
    o.y = f2bf(v.y * s);
    ushort2* xtr = (ushort2*)(xt + (size_t)row * D_FEAT);
    xtr[lane] = o;
}

// Kernel B: histogram of destination rows (int atomics, L2-resident)
__global__ void hist_kernel(const int* __restrict__ rows,
                            int* __restrict__ counts, int n_edges) {
    int e = blockIdx.x * blockDim.x + threadIdx.x;
    if (e < n_edges) atomicAdd(&counts[rows[e]], 1);
}

// Kernel C1: per-block sums of counts (coalesced)
__global__ void scan_sum_kernel(const int* __restrict__ counts,
                                int* __restrict__ blocksums, int n) {
    __shared__ int smem[1024];
    int i = blockIdx.x * 1024 + threadIdx.x;
    smem[threadIdx.x] = (i < n) ? counts[i] : 0;
    __syncthreads();
    for (int off = 512; off > 0; off >>= 1) {
        if (threadIdx.x < off) smem[threadIdx.x] += smem[threadIdx.x + off];
        __syncthreads();
    }
    if (threadIdx.x == 0) blocksums[blockIdx.x] = smem[0];
}

// Kernel C2: one wave scans the block sums (nb <= 64); lane 63 writes total.
__global__ void scan_top_kernel(const int* __restrict__ blocksums,
                                int* __restrict__ blockoffs,
                                int* __restrict__ total_out, int nb) {
    int lane = threadIdx.x;
    int orig = (lane < nb) ? blocksums[lane] : 0;
    int v = orig;
    #pragma unroll
    for (int off = 1; off < 64; off <<= 1) {
        int t = __shfl_up(v, off, 64);
        if (lane >= off) v += t;
    }
    if (lane < nb) blockoffs[lane] = v - orig;
    if (lane == 63) total_out[0] = v;
}

// Kernel C3: block-local exclusive scan + block offset, coalesced writes.
__global__ void scan_apply_kernel(const int* __restrict__ counts,
                                  const int* __restrict__ blockoffs,
                                  int* __restrict__ offsets,
                                  int* __restrict__ cursor, int n) {
    __shared__ int smem[1024];
    int i = blockIdx.x * 1024 + threadIdx.x;
    int v = (i < n) ? counts[i] : 0;
    smem[threadIdx.x] = v;
    __syncthreads();
    for (int off = 1; off < 1024; off <<= 1) {
        int t = (threadIdx.x >= (unsigned)off) ? smem[threadIdx.x - off] : 0;
        __syncthreads();
        smem[threadIdx.x] += t;
        __syncthreads();
    }
    if (i < n) {
        int excl = smem[threadIdx.x] - v + blockoffs[blockIdx.x];
        offsets[i] = excl;
        cursor[i] = excl;
    }
}

// Kernel D: scatter edges into CSR buckets as packed {col, val} (one 8B write)
__global__ void scatter_kernel(const int* __restrict__ rows,
                               const int* __restrict__ cols,
                               const float* __restrict__ vals,
                               int* __restrict__ cursor,
                               int2* __restrict__ packed, int n_edges) {
    int e = blockIdx.x * blockDim.x + threadIdx.x;
    if (e >= n_edges) return;
    int r = rows[e];
    int slot = atomicAdd(&cursor[r], 1);
    int2 p;
    p.x = cols[e];
    p.y = __float_as_int(vals[e]);
    packed[slot] = p;
}

// Kernel E: one wave per output row. Lane l accumulates features [2l, 2l+1]
// from bf16 pre-scaled rows (one dword load per lane per edge).
__global__ void gather_kernel(const unsigned short* __restrict__ xt,
                              const int* __restrict__ offsets,
                              const int2* __restrict__ packed,
                              float* __restrict__ out, int n_nodes) {
    const int lane = threadIdx.x & 63;
    const int wave = threadIdx.x >> 6;
    const int row = blockIdx.x * (blockDim.x >> 6) + wave;
    if (row >= n_nodes) return;

    const int start = offsets[row];
    const int end = offsets[row + 1];

    float2 acc = {0.0f, 0.0f};
    for (int j = start; j < end; ++j) {
        int2 p = packed[j];                 // wave-uniform broadcast load
        float w = __int_as_float(p.y);
        const unsigned* xr = (const unsigned*)(xt + (size_t)p.x * D_FEAT);
        unsigned u = xr[lane];              // 2 bf16 features
        float lo = __uint_as_float(u << 16);
        float hi = __uint_as_float(u & 0xFFFF0000u);
        acc.x += w * lo;
        acc.y += w * hi;
    }
    float2* o = (float2*)(out + (size_t)row * D_FEAT);
    o[lane] = acc;
}

extern "C" void kernel_launch(void* const* d_in, const int* in_sizes, int n_in,
                              void* d_out, int out_size, void* d_ws, size_t ws_size,
                              hipStream_t stream) {
    const float* x    = (const float*)d_in[0];
    const int*   rows = (const int*)d_in[1];
    const int*   cols = (const int*)d_in[2];
    const float* vals = (const float*)d_in[3];
    float* out = (float*)d_out;

    const int n_nodes = in_sizes[0] / D_FEAT;  // 50000
    const int n_edges = in_sizes[1];           // 800000

    // workspace carve-up (4B units)
    char* wsb = (char*)d_ws;
    unsigned short* xt = (unsigned short*)wsb;                   // 12.8 MB
    int*   counts    = (int*)(wsb + 12800000);                   // 200 KB
    int*   offsets   = (int*)(wsb + 12800000 + 200192);          // ~200 KB
    int*   cursor    = (int*)(wsb + 12800000 + 400640);          // 200 KB
    int2*  packed    = (int2*)(wsb + 12800000 + 600832);         // 6.4 MB
    int*   blocksums = (int*)(wsb + 12800000 + 600832 + 6400000);
    int*   blockoffs = blocksums + 64;

    const int nb = (n_nodes + 1023) / 1024;    // 49

    // A: per-node scale + bf16 pre-scaled rows (4 rows per 256-thread block)
    {
        int grid = (n_nodes + 3) / 4;
        hyp_scale_kernel<<<grid, 256, 0, stream>>>(x, xt, n_nodes);
    }
    // zero the histogram (ws is poisoned each launch)
    hipMemsetAsync(counts, 0, (size_t)n_nodes * sizeof(int), stream);
    // B: histogram
    {
        int grid = (n_edges + 255) / 256;
        hist_kernel<<<grid, 256, 0, stream>>>(rows, counts, n_edges);
    }
    // C: hierarchical exclusive scan
    scan_sum_kernel<<<nb, 1024, 0, stream>>>(counts, blocksums, n_nodes);
    scan_top_kernel<<<1, 64, 0, stream>>>(blocksums, blockoffs,
                                          offsets + n_nodes, nb);
    scan_apply_kernel<<<nb, 1024, 0, stream>>>(counts, blockoffs, offsets,
                                               cursor, n_nodes);
    // D: scatter into packed CSR
    {
        int grid = (n_edges + 255) / 256;
        scatter_kernel<<<grid, 256, 0, stream>>>(rows, cols, vals, cursor,
                                                 packed, n_edges);
    }
    // E: gather-reduce, one wave per row
    {
        int grid = (n_nodes + 3) / 4;
        gather_kernel<<<grid, 256, 0, stream>>>(xt, offsets, packed, out,
                                                n_nodes);
    }
}

// Round 5
// 228.862 us; speedup vs baseline: 6.2839x; 1.1655x over previous
//
#include <hip/hip_runtime.h>
#include <math.h>

#define D_FEAT 128

// ---------------- workspace layout ----------------
// xt        : bf16 pre-scaled features, 50000*128*2B = 12.8 MB
// counts    : int[~50048]
// offsets   : int[~50112] (n+1 used)
// cursor    : int[~50048]
// packed    : int2[800000] {col, val_bits} = 6.4 MB
// blocksums : int[64]

static __device__ inline unsigned short f2bf(float f) {
    unsigned u = __float_as_uint(f);
    u += 0x7FFFu + ((u >> 16) & 1u);   // round-to-nearest-even
    return (unsigned short)(u >> 16);
}

// Kernel A (fused): blocks [0, n_scale_blocks) do per-row logmap0 scale +
// bf16 row write (4 rows/block, one wave each); remaining blocks histogram
// 1024 edges each (4 strided edges per thread).
__global__ void scale_hist_kernel(const float* __restrict__ x,
                                  unsigned short* __restrict__ xt,
                                  const int* __restrict__ rows,
                                  int* __restrict__ counts,
                                  int n_nodes, int n_edges,
                                  int n_scale_blocks) {
    if ((int)blockIdx.x < n_scale_blocks) {
        const int lane = threadIdx.x & 63;
        const int wave = threadIdx.x >> 6;
        const int row = blockIdx.x * 4 + wave;
        if (row >= n_nodes) return;

        const float2* xr = (const float2*)(x + (size_t)row * D_FEAT);
        float2 v = xr[lane];
        float ss = v.x * v.x + v.y * v.y;
        #pragma unroll
        for (int off = 32; off > 0; off >>= 1)
            ss += __shfl_xor(ss, off, 64);

        float norm = sqrtf(ss);
        float nc = fmaxf(norm, 1e-15f);
        float u = fminf(nc, 1.0f - 1e-15f);
        float at = 0.5f * (log1pf(u) - log1pf(-u));
        float s = at / nc;

        ushort2 o;
        o.x = f2bf(v.x * s);
        o.y = f2bf(v.y * s);
        ushort2* xtr = (ushort2*)(xt + (size_t)row * D_FEAT);
        xtr[lane] = o;
    } else {
        int base = ((int)blockIdx.x - n_scale_blocks) * 1024 + threadIdx.x;
        #pragma unroll
        for (int k = 0; k < 4; ++k) {
            int e = base + k * 256;
            if (e < n_edges) atomicAdd(&counts[rows[e]], 1);
        }
    }
}

// Kernel C1: per-block sums of counts (coalesced)
__global__ void scan_sum_kernel(const int* __restrict__ counts,
                                int* __restrict__ blocksums, int n) {
    __shared__ int smem[1024];
    int i = blockIdx.x * 1024 + threadIdx.x;
    smem[threadIdx.x] = (i < n) ? counts[i] : 0;
    __syncthreads();
    for (int off = 512; off > 0; off >>= 1) {
        if (threadIdx.x < off) smem[threadIdx.x] += smem[threadIdx.x + off];
        __syncthreads();
    }
    if (threadIdx.x == 0) blocksums[blockIdx.x] = smem[0];
}

// Kernel C2: block-local exclusive scan; each block derives its own block
// offset by wave-reducing blocksums[0..blockIdx.x) (nb <= 64). Last element
// also writes offsets[n].
__global__ void scan_apply_kernel(const int* __restrict__ counts,
                                  const int* __restrict__ blocksums,
                                  int* __restrict__ offsets,
                                  int* __restrict__ cursor, int n) {
    __shared__ int smem[1024];
    __shared__ int s_boff;
    if (threadIdx.x < 64) {
        int v = ((int)threadIdx.x < (int)blockIdx.x) ? blocksums[threadIdx.x] : 0;
        #pragma unroll
        for (int off = 32; off > 0; off >>= 1)
            v += __shfl_xor(v, off, 64);
        if (threadIdx.x == 0) s_boff = v;
    }
    int i = blockIdx.x * 1024 + threadIdx.x;
    int v = (i < n) ? counts[i] : 0;
    smem[threadIdx.x] = v;
    __syncthreads();
    for (int off = 1; off < 1024; off <<= 1) {
        int t = (threadIdx.x >= (unsigned)off) ? smem[threadIdx.x - off] : 0;
        __syncthreads();
        smem[threadIdx.x] += t;
        __syncthreads();
    }
    if (i < n) {
        int excl = smem[threadIdx.x] - v + s_boff;
        offsets[i] = excl;
        cursor[i] = excl;
        if (i == n - 1) offsets[n] = excl + v;
    }
}

// Kernel D: scatter edges into packed CSR; 4 strided edges per thread for MLP.
__global__ void scatter_kernel(const int* __restrict__ rows,
                               const int* __restrict__ cols,
                               const float* __restrict__ vals,
                               int* __restrict__ cursor,
                               int2* __restrict__ packed, int n_edges) {
    int base = blockIdx.x * 1024 + threadIdx.x;
    #pragma unroll
    for (int k = 0; k < 4; ++k) {
        int e = base + k * 256;
        if (e < n_edges) {
            int r = rows[e];
            int slot = atomicAdd(&cursor[r], 1);
            int2 p;
            p.x = cols[e];
            p.y = __float_as_int(vals[e]);
            packed[slot] = p;
        }
    }
}

// Kernel E: one wave per output row. Coalesced preload of up to 64 packed
// edges into registers, shfl-broadcast per edge, 4-wide unrolled row loads.
__global__ void gather_kernel(const unsigned short* __restrict__ xt,
                              const int* __restrict__ offsets,
                              const int2* __restrict__ packed,
                              float* __restrict__ out, int n_nodes) {
    const int lane = threadIdx.x & 63;
    const int wave = threadIdx.x >> 6;
    const int row = blockIdx.x * 4 + wave;
    if (row >= n_nodes) return;

    const int start = offsets[row];
    const int end = offsets[row + 1];
    const int deg = end - start;

    int2 myp = {0, 0};
    if (lane < deg) myp = packed[start + lane];   // coalesced
    int pc = myp.x;
    float pw = __int_as_float(myp.y);

    float accx = 0.0f, accy = 0.0f;
    const int m = deg < 64 ? deg : 64;
    int j = 0;
    for (; j + 4 <= m; j += 4) {
        int c0 = __shfl(pc, j, 64);
        int c1 = __shfl(pc, j + 1, 64);
        int c2 = __shfl(pc, j + 2, 64);
        int c3 = __shfl(pc, j + 3, 64);
        float w0 = __shfl(pw, j, 64);
        float w1 = __shfl(pw, j + 1, 64);
        float w2 = __shfl(pw, j + 2, 64);
        float w3 = __shfl(pw, j + 3, 64);
        unsigned u0 = ((const unsigned*)(xt + ((size_t)c0 << 7)))[lane];
        unsigned u1 = ((const unsigned*)(xt + ((size_t)c1 << 7)))[lane];
        unsigned u2 = ((const unsigned*)(xt + ((size_t)c2 << 7)))[lane];
        unsigned u3 = ((const unsigned*)(xt + ((size_t)c3 << 7)))[lane];
        accx = fmaf(w0, __uint_as_float(u0 << 16), accx);
        accy = fmaf(w0, __uint_as_float(u0 & 0xFFFF0000u), accy);
        accx = fmaf(w1, __uint_as_float(u1 << 16), accx);
        accy = fmaf(w1, __uint_as_float(u1 & 0xFFFF0000u), accy);
        accx = fmaf(w2, __uint_as_float(u2 << 16), accx);
        accy = fmaf(w2, __uint_as_float(u2 & 0xFFFF0000u), accy);
        accx = fmaf(w3, __uint_as_float(u3 << 16), accx);
        accy = fmaf(w3, __uint_as_float(u3 & 0xFFFF0000u), accy);
    }
    for (; j < m; ++j) {
        int c = __shfl(pc, j, 64);
        float w = __shfl(pw, j, 64);
        unsigned u = ((const unsigned*)(xt + ((size_t)c << 7)))[lane];
        accx = fmaf(w, __uint_as_float(u << 16), accx);
        accy = fmaf(w, __uint_as_float(u & 0xFFFF0000u), accy);
    }
    // rare: rows with degree > 64
    for (int jj = start + 64; jj < end; ++jj) {
        int2 p = packed[jj];
        float w = __int_as_float(p.y);
        unsigned u = ((const unsigned*)(xt + ((size_t)p.x << 7)))[lane];
        accx = fmaf(w, __uint_as_float(u << 16), accx);
        accy = fmaf(w, __uint_as_float(u & 0xFFFF0000u), accy);
    }

    float2 o;
    o.x = accx;
    o.y = accy;
    ((float2*)(out + ((size_t)row << 7)))[lane] = o;
}

extern "C" void kernel_launch(void* const* d_in, const int* in_sizes, int n_in,
                              void* d_out, int out_size, void* d_ws, size_t ws_size,
                              hipStream_t stream) {
    const float* x    = (const float*)d_in[0];
    const int*   rows = (const int*)d_in[1];
    const int*   cols = (const int*)d_in[2];
    const float* vals = (const float*)d_in[3];
    float* out = (float*)d_out;

    const int n_nodes = in_sizes[0] / D_FEAT;  // 50000
    const int n_edges = in_sizes[1];           // 800000

    char* wsb = (char*)d_ws;
    unsigned short* xt = (unsigned short*)wsb;                   // 12.8 MB
    int*   counts    = (int*)(wsb + 12800000);                   // 200 KB
    int*   offsets   = (int*)(wsb + 12800000 + 200192);          // ~200 KB
    int*   cursor    = (int*)(wsb + 12800000 + 400640);          // 200 KB
    int2*  packed    = (int2*)(wsb + 12800000 + 600832);         // 6.4 MB
    int*   blocksums = (int*)(wsb + 12800000 + 600832 + 6400000);

    const int nb = (n_nodes + 1023) / 1024;           // 49
    const int n_scale_blocks = (n_nodes + 3) / 4;     // 12500
    const int n_hist_blocks = (n_edges + 1023) / 1024;

    // zero the histogram (ws is poisoned each launch)
    hipMemsetAsync(counts, 0, (size_t)n_nodes * sizeof(int), stream);
    // A: fused scale(+bf16 rows) and histogram
    scale_hist_kernel<<<n_scale_blocks + n_hist_blocks, 256, 0, stream>>>(
        x, xt, rows, counts, n_nodes, n_edges, n_scale_blocks);
    // C: hierarchical exclusive scan (2 launches)
    scan_sum_kernel<<<nb, 1024, 0, stream>>>(counts, blocksums, n_nodes);
    scan_apply_kernel<<<nb, 1024, 0, stream>>>(counts, blocksums, offsets,
                                               cursor, n_nodes);
    // D: scatter into packed CSR
    scatter_kernel<<<(n_edges + 1023) / 1024, 256, 0, stream>>>(
        rows, cols, vals, cursor, packed, n_edges);
    // E: gather-reduce, one wave per row
    gather_kernel<<<(n_nodes + 3) / 4, 256, 0, stream>>>(
        xt, offsets, packed, out, n_nodes);
}

// Round 6
// 175.800 us; speedup vs baseline: 8.1805x; 1.3018x over previous
//
#include <hip/hip_runtime.h>
#include <math.h>

#define D_FEAT 128
#define CAP 64      // fixed bucket capacity per row (Poisson(16): P(deg>64)~1e-18)
#define OCAP 1024   // overflow list capacity

static __device__ inline unsigned short f2bf(float f) {
    unsigned u = __float_as_uint(f);
    u += 0x7FFFu + ((u >> 16) & 1u);   // round-to-nearest-even
    return (unsigned short)(u >> 16);
}

// ===================== fast path (fixed buckets, 1 atomic pass) =============

// Fused: blocks [0, n_scatter_blocks) scatter edges into fixed-cap buckets
// (1024 edges/block, 4 strided per thread). Remaining blocks do per-row
// logmap0 scale + bf16 row write (4 rows/block, one wave each). Scatter
// blocks are dispatched FIRST so their atomic-latency waves are resident
// early and the scale blocks' VALU/BW work overlaps them.
__global__ void scatter_scale_kernel(const float* __restrict__ x,
                                     unsigned short* __restrict__ xt,
                                     const int* __restrict__ rows,
                                     const int* __restrict__ cols,
                                     const float* __restrict__ vals,
                                     int* __restrict__ cnt,
                                     int2* __restrict__ buckets,
                                     int* __restrict__ ocount,
                                     int4* __restrict__ oedges,
                                     int n_nodes, int n_edges,
                                     int n_scatter_blocks) {
    if ((int)blockIdx.x < n_scatter_blocks) {
        int base = blockIdx.x * 1024 + threadIdx.x;
        #pragma unroll
        for (int k = 0; k < 4; ++k) {
            int e = base + k * 256;
            if (e < n_edges) {
                int r = rows[e];
                int slot = atomicAdd(&cnt[r], 1);
                int2 p;
                p.x = cols[e];
                p.y = __float_as_int(vals[e]);
                if (slot < CAP) {
                    buckets[(size_t)r * CAP + slot] = p;
                } else {  // astronomically rare; handled by cleanup_kernel
                    int o = atomicAdd(ocount, 1);
                    if (o < OCAP) {
                        int4 q; q.x = r; q.y = p.x; q.z = p.y; q.w = 0;
                        oedges[o] = q;
                    }
                }
            }
        }
    } else {
        const int lane = threadIdx.x & 63;
        const int wave = threadIdx.x >> 6;
        const int row = ((int)blockIdx.x - n_scatter_blocks) * 4 + wave;
        if (row >= n_nodes) return;

        const float2* xr = (const float2*)(x + (size_t)row * D_FEAT);
        float2 v = xr[lane];
        float ss = v.x * v.x + v.y * v.y;
        #pragma unroll
        for (int off = 32; off > 0; off >>= 1)
            ss += __shfl_xor(ss, off, 64);

        float norm = sqrtf(ss);
        float nc = fmaxf(norm, 1e-15f);
        float u = fminf(nc, 1.0f - 1e-15f);
        float at = 0.5f * (log1pf(u) - log1pf(-u));
        float s = at / nc;

        ushort2 o;
        o.x = f2bf(v.x * s);
        o.y = f2bf(v.y * s);
        ((ushort2*)(xt + (size_t)row * D_FEAT))[lane] = o;
    }
}

// Gather: one wave per row; coalesced bucket preload + shfl broadcast,
// 4-wide unrolled independent row loads.
__global__ void gather_bucket_kernel(const unsigned short* __restrict__ xt,
                                     const int* __restrict__ cnt,
                                     const int2* __restrict__ buckets,
                                     float* __restrict__ out, int n_nodes) {
    const int lane = threadIdx.x & 63;
    const int wave = threadIdx.x >> 6;
    const int row = blockIdx.x * 4 + wave;
    if (row >= n_nodes) return;

    int deg = cnt[row];
    deg = deg < CAP ? deg : CAP;

    int2 myp = {0, 0};
    if (lane < deg) myp = buckets[(size_t)row * CAP + lane];  // coalesced
    int pc = myp.x;
    float pw = __int_as_float(myp.y);

    float accx = 0.0f, accy = 0.0f;
    int j = 0;
    for (; j + 4 <= deg; j += 4) {
        int c0 = __shfl(pc, j, 64);
        int c1 = __shfl(pc, j + 1, 64);
        int c2 = __shfl(pc, j + 2, 64);
        int c3 = __shfl(pc, j + 3, 64);
        float w0 = __shfl(pw, j, 64);
        float w1 = __shfl(pw, j + 1, 64);
        float w2 = __shfl(pw, j + 2, 64);
        float w3 = __shfl(pw, j + 3, 64);
        unsigned u0 = ((const unsigned*)(xt + ((size_t)c0 << 7)))[lane];
        unsigned u1 = ((const unsigned*)(xt + ((size_t)c1 << 7)))[lane];
        unsigned u2 = ((const unsigned*)(xt + ((size_t)c2 << 7)))[lane];
        unsigned u3 = ((const unsigned*)(xt + ((size_t)c3 << 7)))[lane];
        accx = fmaf(w0, __uint_as_float(u0 << 16), accx);
        accy = fmaf(w0, __uint_as_float(u0 & 0xFFFF0000u), accy);
        accx = fmaf(w1, __uint_as_float(u1 << 16), accx);
        accy = fmaf(w1, __uint_as_float(u1 & 0xFFFF0000u), accy);
        accx = fmaf(w2, __uint_as_float(u2 << 16), accx);
        accy = fmaf(w2, __uint_as_float(u2 & 0xFFFF0000u), accy);
        accx = fmaf(w3, __uint_as_float(u3 << 16), accx);
        accy = fmaf(w3, __uint_as_float(u3 & 0xFFFF0000u), accy);
    }
    for (; j < deg; ++j) {
        int c = __shfl(pc, j, 64);
        float w = __shfl(pw, j, 64);
        unsigned u = ((const unsigned*)(xt + ((size_t)c << 7)))[lane];
        accx = fmaf(w, __uint_as_float(u << 16), accx);
        accy = fmaf(w, __uint_as_float(u & 0xFFFF0000u), accy);
    }

    float2 o;
    o.x = accx;
    o.y = accy;
    ((float2*)(out + ((size_t)row << 7)))[lane] = o;
}

// Cleanup: process overflow edges (normally zero) — 32 threads/edge,
// atomic add into out AFTER gather wrote it.
__global__ void cleanup_kernel(const unsigned short* __restrict__ xt,
                               const int* __restrict__ ocount,
                               const int4* __restrict__ oedges,
                               float* __restrict__ out) {
    int t = blockIdx.x * blockDim.x + threadIdx.x;
    int e = t >> 5, sub = t & 31;
    int n = *ocount;
    n = n < OCAP ? n : OCAP;
    if (e >= n) return;
    int4 q = oedges[e];
    float w = __int_as_float(q.z);
    const unsigned* xr = (const unsigned*)(xt + ((size_t)q.y << 7));
    unsigned u0 = xr[sub * 2], u1 = xr[sub * 2 + 1];
    float* o = out + ((size_t)q.x << 7) + sub * 4;
    atomicAdd(o + 0, w * __uint_as_float(u0 << 16));
    atomicAdd(o + 1, w * __uint_as_float(u0 & 0xFFFF0000u));
    atomicAdd(o + 2, w * __uint_as_float(u1 << 16));
    atomicAdd(o + 3, w * __uint_as_float(u1 & 0xFFFF0000u));
}

// ===================== fallback path (R5 structure, ~19.9 MB ws) ============

__global__ void scale_hist_kernel(const float* __restrict__ x,
                                  unsigned short* __restrict__ xt,
                                  const int* __restrict__ rows,
                                  int* __restrict__ counts,
                                  int n_nodes, int n_edges,
                                  int n_scale_blocks) {
    if ((int)blockIdx.x < n_scale_blocks) {
        const int lane = threadIdx.x & 63;
        const int wave = threadIdx.x >> 6;
        const int row = blockIdx.x * 4 + wave;
        if (row >= n_nodes) return;
        const float2* xr = (const float2*)(x + (size_t)row * D_FEAT);
        float2 v = xr[lane];
        float ss = v.x * v.x + v.y * v.y;
        #pragma unroll
        for (int off = 32; off > 0; off >>= 1)
            ss += __shfl_xor(ss, off, 64);
        float norm = sqrtf(ss);
        float nc = fmaxf(norm, 1e-15f);
        float u = fminf(nc, 1.0f - 1e-15f);
        float at = 0.5f * (log1pf(u) - log1pf(-u));
        float s = at / nc;
        ushort2 o;
        o.x = f2bf(v.x * s);
        o.y = f2bf(v.y * s);
        ((ushort2*)(xt + (size_t)row * D_FEAT))[lane] = o;
    } else {
        int base = ((int)blockIdx.x - n_scale_blocks) * 1024 + threadIdx.x;
        #pragma unroll
        for (int k = 0; k < 4; ++k) {
            int e = base + k * 256;
            if (e < n_edges) atomicAdd(&counts[rows[e]], 1);
        }
    }
}

__global__ void scan_sum_kernel(const int* __restrict__ counts,
                                int* __restrict__ blocksums, int n) {
    __shared__ int smem[1024];
    int i = blockIdx.x * 1024 + threadIdx.x;
    smem[threadIdx.x] = (i < n) ? counts[i] : 0;
    __syncthreads();
    for (int off = 512; off > 0; off >>= 1) {
        if (threadIdx.x < off) smem[threadIdx.x] += smem[threadIdx.x + off];
        __syncthreads();
    }
    if (threadIdx.x == 0) blocksums[blockIdx.x] = smem[0];
}

__global__ void scan_apply_kernel(const int* __restrict__ counts,
                                  const int* __restrict__ blocksums,
                                  int* __restrict__ offsets,
                                  int* __restrict__ cursor, int n) {
    __shared__ int smem[1024];
    __shared__ int s_boff;
    if (threadIdx.x < 64) {
        int v = ((int)threadIdx.x < (int)blockIdx.x) ? blocksums[threadIdx.x] : 0;
        #pragma unroll
        for (int off = 32; off > 0; off >>= 1)
            v += __shfl_xor(v, off, 64);
        if (threadIdx.x == 0) s_boff = v;
    }
    int i = blockIdx.x * 1024 + threadIdx.x;
    int v = (i < n) ? counts[i] : 0;
    smem[threadIdx.x] = v;
    __syncthreads();
    for (int off = 1; off < 1024; off <<= 1) {
        int t = (threadIdx.x >= (unsigned)off) ? smem[threadIdx.x - off] : 0;
        __syncthreads();
        smem[threadIdx.x] += t;
        __syncthreads();
    }
    if (i < n) {
        int excl = smem[threadIdx.x] - v + s_boff;
        offsets[i] = excl;
        cursor[i] = excl;
        if (i == n - 1) offsets[n] = excl + v;
    }
}

__global__ void scatter_kernel(const int* __restrict__ rows,
                               const int* __restrict__ cols,
                               const float* __restrict__ vals,
                               int* __restrict__ cursor,
                               int2* __restrict__ packed, int n_edges) {
    int base = blockIdx.x * 1024 + threadIdx.x;
    #pragma unroll
    for (int k = 0; k < 4; ++k) {
        int e = base + k * 256;
        if (e < n_edges) {
            int r = rows[e];
            int slot = atomicAdd(&cursor[r], 1);
            int2 p;
            p.x = cols[e];
            p.y = __float_as_int(vals[e]);
            packed[slot] = p;
        }
    }
}

__global__ void gather_kernel(const unsigned short* __restrict__ xt,
                              const int* __restrict__ offsets,
                              const int2* __restrict__ packed,
                              float* __restrict__ out, int n_nodes) {
    const int lane = threadIdx.x & 63;
    const int wave = threadIdx.x >> 6;
    const int row = blockIdx.x * 4 + wave;
    if (row >= n_nodes) return;
    const int start = offsets[row];
    const int end = offsets[row + 1];
    const int deg = end - start;
    int2 myp = {0, 0};
    if (lane < deg) myp = packed[start + lane];
    int pc = myp.x;
    float pw = __int_as_float(myp.y);
    float accx = 0.0f, accy = 0.0f;
    const int m = deg < 64 ? deg : 64;
    int j = 0;
    for (; j + 4 <= m; j += 4) {
        int c0 = __shfl(pc, j, 64);
        int c1 = __shfl(pc, j + 1, 64);
        int c2 = __shfl(pc, j + 2, 64);
        int c3 = __shfl(pc, j + 3, 64);
        float w0 = __shfl(pw, j, 64);
        float w1 = __shfl(pw, j + 1, 64);
        float w2 = __shfl(pw, j + 2, 64);
        float w3 = __shfl(pw, j + 3, 64);
        unsigned u0 = ((const unsigned*)(xt + ((size_t)c0 << 7)))[lane];
        unsigned u1 = ((const unsigned*)(xt + ((size_t)c1 << 7)))[lane];
        unsigned u2 = ((const unsigned*)(xt + ((size_t)c2 << 7)))[lane];
        unsigned u3 = ((const unsigned*)(xt + ((size_t)c3 << 7)))[lane];
        accx = fmaf(w0, __uint_as_float(u0 << 16), accx);
        accy = fmaf(w0, __uint_as_float(u0 & 0xFFFF0000u), accy);
        accx = fmaf(w1, __uint_as_float(u1 << 16), accx);
        accy = fmaf(w1, __uint_as_float(u1 & 0xFFFF0000u), accy);
        accx = fmaf(w2, __uint_as_float(u2 << 16), accx);
        accy = fmaf(w2, __uint_as_float(u2 & 0xFFFF0000u), accy);
        accx = fmaf(w3, __uint_as_float(u3 << 16), accx);
        accy = fmaf(w3, __uint_as_float(u3 & 0xFFFF0000u), accy);
    }
    for (; j < m; ++j) {
        int c = __shfl(pc, j, 64);
        float w = __shfl(pw, j, 64);
        unsigned u = ((const unsigned*)(xt + ((size_t)c << 7)))[lane];
        accx = fmaf(w, __uint_as_float(u << 16), accx);
        accy = fmaf(w, __uint_as_float(u & 0xFFFF0000u), accy);
    }
    for (int jj = start + 64; jj < end; ++jj) {
        int2 p = packed[jj];
        float w = __int_as_float(p.y);
        unsigned u = ((const unsigned*)(xt + ((size_t)p.x << 7)))[lane];
        accx = fmaf(w, __uint_as_float(u << 16), accx);
        accy = fmaf(w, __uint_as_float(u & 0xFFFF0000u), accy);
    }
    float2 o;
    o.x = accx;
    o.y = accy;
    ((float2*)(out + ((size_t)row << 7)))[lane] = o;
}

// ============================================================================

extern "C" void kernel_launch(void* const* d_in, const int* in_sizes, int n_in,
                              void* d_out, int out_size, void* d_ws, size_t ws_size,
                              hipStream_t stream) {
    const float* x    = (const float*)d_in[0];
    const int*   rows = (const int*)d_in[1];
    const int*   cols = (const int*)d_in[2];
    const float* vals = (const float*)d_in[3];
    float* out = (float*)d_out;

    const int n_nodes = in_sizes[0] / D_FEAT;  // 50000
    const int n_edges = in_sizes[1];           // 800000

    char* wsb = (char*)d_ws;
    const int n_scatter_blocks = (n_edges + 1023) / 1024;  // 782
    const int n_scale_blocks = (n_nodes + 3) / 4;          // 12500

    // fast-path layout
    size_t xt_bytes    = (size_t)n_nodes * D_FEAT * 2;            // 12.8 MB
    size_t cnt_off     = xt_bytes;
    size_t ocount_off  = cnt_off + (size_t)n_nodes * 4;
    size_t oedges_off  = (ocount_off + 4 + 255) & ~(size_t)255;
    size_t buckets_off = (oedges_off + (size_t)OCAP * 16 + 511) & ~(size_t)511;
    size_t need        = buckets_off + (size_t)n_nodes * CAP * 8; // ~38.6 MB

    if (ws_size >= need) {
        unsigned short* xt = (unsigned short*)wsb;
        int*  cnt     = (int*)(wsb + cnt_off);
        int*  ocount  = (int*)(wsb + ocount_off);
        int4* oedges  = (int4*)(wsb + oedges_off);
        int2* buckets = (int2*)(wsb + buckets_off);

        // zero cnt + ocount in one memset
        hipMemsetAsync(cnt, 0, ocount_off + 4 - cnt_off, stream);
        // fused scatter (first) + scale
        scatter_scale_kernel<<<n_scatter_blocks + n_scale_blocks, 256, 0, stream>>>(
            x, xt, rows, cols, vals, cnt, buckets, ocount, oedges,
            n_nodes, n_edges, n_scatter_blocks);
        // gather
        gather_bucket_kernel<<<(n_nodes + 3) / 4, 256, 0, stream>>>(
            xt, cnt, buckets, out, n_nodes);
        // overflow cleanup (normally a no-op)
        cleanup_kernel<<<(OCAP * 32) / 256, 256, 0, stream>>>(xt, ocount, oedges, out);
    } else {
        // R5 fallback (~19.9 MB)
        unsigned short* xt = (unsigned short*)wsb;
        int*  counts    = (int*)(wsb + 12800000);
        int*  offsets   = (int*)(wsb + 12800000 + 200192);
        int*  cursor    = (int*)(wsb + 12800000 + 400640);
        int2* packed    = (int2*)(wsb + 12800000 + 600832);
        int*  blocksums = (int*)(wsb + 12800000 + 600832 + 6400000);
        const int nb = (n_nodes + 1023) / 1024;

        hipMemsetAsync(counts, 0, (size_t)n_nodes * sizeof(int), stream);
        scale_hist_kernel<<<n_scale_blocks + n_scatter_blocks, 256, 0, stream>>>(
            x, xt, rows, counts, n_nodes, n_edges, n_scale_blocks);
        scan_sum_kernel<<<nb, 1024, 0, stream>>>(counts, blocksums, n_nodes);
        scan_apply_kernel<<<nb, 1024, 0, stream>>>(counts, blocksums, offsets,
                                                   cursor, n_nodes);
        scatter_kernel<<<n_scatter_blocks, 256, 0, stream>>>(
            rows, cols, vals, cursor, packed, n_edges);
        gather_kernel<<<(n_nodes + 3) / 4, 256, 0, stream>>>(
            xt, offsets, packed, out, n_nodes);
    }
}

// Round 7
// 167.968 us; speedup vs baseline: 8.5620x; 1.0466x over previous
//
#include <hip/hip_runtime.h>
#include <math.h>

#define D_FEAT 128
#define CAP 64      // bucket capacity/row; 512B row stride => line-aligned rows
#define OCAP 1024   // overflow list capacity

static __device__ inline unsigned short f2bf(float f) {
    unsigned u = __float_as_uint(f);
    u += 0x7FFFu + ((u >> 16) & 1u);   // round-to-nearest-even
    return (unsigned short)(u >> 16);
}

// ===================== fast path ===========================================
// Fused kernel. Scatter role (blocks [0, n_scatter_blocks), dispatched first):
// edges are partitioned by home XCD = rows[e] & 7. Each 1024-edge chunk is
// scanned by 8 consecutive blocks; block (8c + p) processes only edges with
// (row & 7) == p. With round-robin blockIdx->XCD this makes every bucket
// line dirty in exactly ONE XCD's L2 (buckets rows are 512B aligned), killing
// the cross-XCD partial-line writeback storm seen in R6 (50MB -> ~8MB).
// Scale role (remaining blocks): per-row logmap0 scale + bf16 row write.
__global__ void scatter_scale_kernel(const float* __restrict__ x,
                                     unsigned short* __restrict__ xt,
                                     const int* __restrict__ rows,
                                     const int* __restrict__ cols,
                                     const float* __restrict__ vals,
                                     int* __restrict__ cnt,
                                     int2* __restrict__ buckets,
                                     int* __restrict__ ocount,
                                     int4* __restrict__ oedges,
                                     int n_nodes, int n_edges,
                                     int n_scatter_blocks) {
    if ((int)blockIdx.x < n_scatter_blocks) {
        const int xcd = blockIdx.x & 7;
        const int chunk = blockIdx.x >> 3;
        int base = chunk * 1024 + threadIdx.x;
        #pragma unroll
        for (int k = 0; k < 4; ++k) {
            int e = base + k * 256;
            if (e < n_edges) {
                int r = rows[e];
                if ((r & 7) == xcd) {
                    int slot = atomicAdd(&cnt[r], 1);
                    int2 p;
                    p.x = cols[e];
                    p.y = __float_as_int(vals[e]);
                    if (slot < CAP) {
                        buckets[(size_t)r * CAP + slot] = p;
                    } else {  // astronomically rare
                        int o = atomicAdd(ocount, 1);
                        if (o < OCAP) {
                            int4 q; q.x = r; q.y = p.x; q.z = p.y; q.w = 0;
                            oedges[o] = q;
                        }
                    }
                }
            }
        }
    } else {
        const int lane = threadIdx.x & 63;
        const int wave = threadIdx.x >> 6;
        const int row = ((int)blockIdx.x - n_scatter_blocks) * 4 + wave;
        if (row >= n_nodes) return;

        const float2* xr = (const float2*)(x + (size_t)row * D_FEAT);
        float2 v = xr[lane];
        float ss = v.x * v.x + v.y * v.y;
        #pragma unroll
        for (int off = 32; off > 0; off >>= 1)
            ss += __shfl_xor(ss, off, 64);

        float norm = sqrtf(ss);
        float nc = fmaxf(norm, 1e-15f);
        float u = fminf(nc, 1.0f - 1e-15f);
        float at = 0.5f * (log1pf(u) - log1pf(-u));
        float s = at / nc;

        ushort2 o;
        o.x = f2bf(v.x * s);
        o.y = f2bf(v.y * s);
        ((ushort2*)(xt + (size_t)row * D_FEAT))[lane] = o;
    }
}

// Gather: one wave per row, rows mapped so a block's rows share the XCD that
// scattered them (blockIdx & 7 == row & 7). Coalesced bucket preload + shfl
// broadcast; 8-wide unrolled independent row loads (avg deg 16 -> 2 rounds).
__global__ void gather_bucket_kernel(const unsigned short* __restrict__ xt,
                                     const int* __restrict__ cnt,
                                     const int2* __restrict__ buckets,
                                     float* __restrict__ out, int n_nodes) {
    const int lane = threadIdx.x & 63;
    const int wave = threadIdx.x >> 6;
    const int xcd = blockIdx.x & 7;
    const int idx = blockIdx.x >> 3;
    const int m = idx * 4 + wave;
    const int row = xcd + (m << 3);
    if (row >= n_nodes) return;

    int deg = cnt[row];
    deg = deg < CAP ? deg : CAP;

    int2 myp = {0, 0};
    if (lane < deg) myp = buckets[(size_t)row * CAP + lane];  // coalesced
    int pc = myp.x;
    float pw = __int_as_float(myp.y);

    float accx = 0.0f, accy = 0.0f;
    int j = 0;
    for (; j + 8 <= deg; j += 8) {
        int c0 = __shfl(pc, j, 64),     c1 = __shfl(pc, j + 1, 64);
        int c2 = __shfl(pc, j + 2, 64), c3 = __shfl(pc, j + 3, 64);
        int c4 = __shfl(pc, j + 4, 64), c5 = __shfl(pc, j + 5, 64);
        int c6 = __shfl(pc, j + 6, 64), c7 = __shfl(pc, j + 7, 64);
        float w0 = __shfl(pw, j, 64),     w1 = __shfl(pw, j + 1, 64);
        float w2 = __shfl(pw, j + 2, 64), w3 = __shfl(pw, j + 3, 64);
        float w4 = __shfl(pw, j + 4, 64), w5 = __shfl(pw, j + 5, 64);
        float w6 = __shfl(pw, j + 6, 64), w7 = __shfl(pw, j + 7, 64);
        unsigned u0 = ((const unsigned*)(xt + ((size_t)c0 << 7)))[lane];
        unsigned u1 = ((const unsigned*)(xt + ((size_t)c1 << 7)))[lane];
        unsigned u2 = ((const unsigned*)(xt + ((size_t)c2 << 7)))[lane];
        unsigned u3 = ((const unsigned*)(xt + ((size_t)c3 << 7)))[lane];
        unsigned u4 = ((const unsigned*)(xt + ((size_t)c4 << 7)))[lane];
        unsigned u5 = ((const unsigned*)(xt + ((size_t)c5 << 7)))[lane];
        unsigned u6 = ((const unsigned*)(xt + ((size_t)c6 << 7)))[lane];
        unsigned u7 = ((const unsigned*)(xt + ((size_t)c7 << 7)))[lane];
        accx = fmaf(w0, __uint_as_float(u0 << 16), accx);
        accy = fmaf(w0, __uint_as_float(u0 & 0xFFFF0000u), accy);
        accx = fmaf(w1, __uint_as_float(u1 << 16), accx);
        accy = fmaf(w1, __uint_as_float(u1 & 0xFFFF0000u), accy);
        accx = fmaf(w2, __uint_as_float(u2 << 16), accx);
        accy = fmaf(w2, __uint_as_float(u2 & 0xFFFF0000u), accy);
        accx = fmaf(w3, __uint_as_float(u3 << 16), accx);
        accy = fmaf(w3, __uint_as_float(u3 & 0xFFFF0000u), accy);
        accx = fmaf(w4, __uint_as_float(u4 << 16), accx);
        accy = fmaf(w4, __uint_as_float(u4 & 0xFFFF0000u), accy);
        accx = fmaf(w5, __uint_as_float(u5 << 16), accx);
        accy = fmaf(w5, __uint_as_float(u5 & 0xFFFF0000u), accy);
        accx = fmaf(w6, __uint_as_float(u6 << 16), accx);
        accy = fmaf(w6, __uint_as_float(u6 & 0xFFFF0000u), accy);
        accx = fmaf(w7, __uint_as_float(u7 << 16), accx);
        accy = fmaf(w7, __uint_as_float(u7 & 0xFFFF0000u), accy);
    }
    for (; j + 4 <= deg; j += 4) {
        int c0 = __shfl(pc, j, 64),     c1 = __shfl(pc, j + 1, 64);
        int c2 = __shfl(pc, j + 2, 64), c3 = __shfl(pc, j + 3, 64);
        float w0 = __shfl(pw, j, 64),     w1 = __shfl(pw, j + 1, 64);
        float w2 = __shfl(pw, j + 2, 64), w3 = __shfl(pw, j + 3, 64);
        unsigned u0 = ((const unsigned*)(xt + ((size_t)c0 << 7)))[lane];
        unsigned u1 = ((const unsigned*)(xt + ((size_t)c1 << 7)))[lane];
        unsigned u2 = ((const unsigned*)(xt + ((size_t)c2 << 7)))[lane];
        unsigned u3 = ((const unsigned*)(xt + ((size_t)c3 << 7)))[lane];
        accx = fmaf(w0, __uint_as_float(u0 << 16), accx);
        accy = fmaf(w0, __uint_as_float(u0 & 0xFFFF0000u), accy);
        accx = fmaf(w1, __uint_as_float(u1 << 16), accx);
        accy = fmaf(w1, __uint_as_float(u1 & 0xFFFF0000u), accy);
        accx = fmaf(w2, __uint_as_float(u2 << 16), accx);
        accy = fmaf(w2, __uint_as_float(u2 & 0xFFFF0000u), accy);
        accx = fmaf(w3, __uint_as_float(u3 << 16), accx);
        accy = fmaf(w3, __uint_as_float(u3 & 0xFFFF0000u), accy);
    }
    for (; j < deg; ++j) {
        int c = __shfl(pc, j, 64);
        float w = __shfl(pw, j, 64);
        unsigned u = ((const unsigned*)(xt + ((size_t)c << 7)))[lane];
        accx = fmaf(w, __uint_as_float(u << 16), accx);
        accy = fmaf(w, __uint_as_float(u & 0xFFFF0000u), accy);
    }

    float2 o;
    o.x = accx;
    o.y = accy;
    ((float2*)(out + ((size_t)row << 7)))[lane] = o;
}

// Cleanup: overflow edges (normally zero) — atomic add into out after gather.
__global__ void cleanup_kernel(const unsigned short* __restrict__ xt,
                               const int* __restrict__ ocount,
                               const int4* __restrict__ oedges,
                               float* __restrict__ out) {
    int t = blockIdx.x * blockDim.x + threadIdx.x;
    int e = t >> 5, sub = t & 31;
    int n = *ocount;
    n = n < OCAP ? n : OCAP;
    if (e >= n) return;
    int4 q = oedges[e];
    float w = __int_as_float(q.z);
    const unsigned* xr = (const unsigned*)(xt + ((size_t)q.y << 7));
    unsigned u0 = xr[sub * 2], u1 = xr[sub * 2 + 1];
    float* o = out + ((size_t)q.x << 7) + sub * 4;
    atomicAdd(o + 0, w * __uint_as_float(u0 << 16));
    atomicAdd(o + 1, w * __uint_as_float(u0 & 0xFFFF0000u));
    atomicAdd(o + 2, w * __uint_as_float(u1 << 16));
    atomicAdd(o + 3, w * __uint_as_float(u1 & 0xFFFF0000u));
}

// ===================== fallback (tiny ws; never expected) ===================
__global__ void fallback_kernel(const float* __restrict__ x,
                                const int* __restrict__ rows,
                                const int* __restrict__ cols,
                                const float* __restrict__ vals,
                                float* __restrict__ out, int n_edges) {
    int gid = blockIdx.x * blockDim.x + threadIdx.x;
    int e = gid >> 5, t = gid & 31;
    if (e >= n_edges) return;
    int c = cols[e];
    const float* xr = x + (size_t)c * D_FEAT;
    float ss = 0.0f;
    for (int i = 0; i < D_FEAT; ++i) ss += xr[i] * xr[i];
    float nc = fmaxf(sqrtf(ss), 1e-15f);
    float u = fminf(nc, 1.0f - 1e-15f);
    float w = vals[e] * (0.5f * (log1pf(u) - log1pf(-u))) / nc;
    const float4* xc = (const float4*)xr;
    float4 xv = xc[t];
    float* o = out + (size_t)rows[e] * D_FEAT + t * 4;
    atomicAdd(o + 0, w * xv.x);
    atomicAdd(o + 1, w * xv.y);
    atomicAdd(o + 2, w * xv.z);
    atomicAdd(o + 3, w * xv.w);
}

// ============================================================================

extern "C" void kernel_launch(void* const* d_in, const int* in_sizes, int n_in,
                              void* d_out, int out_size, void* d_ws, size_t ws_size,
                              hipStream_t stream) {
    const float* x    = (const float*)d_in[0];
    const int*   rows = (const int*)d_in[1];
    const int*   cols = (const int*)d_in[2];
    const float* vals = (const float*)d_in[3];
    float* out = (float*)d_out;

    const int n_nodes = in_sizes[0] / D_FEAT;  // 50000
    const int n_edges = in_sizes[1];           // 800000

    char* wsb = (char*)d_ws;
    const int n_chunks = (n_edges + 1023) / 1024;          // 782
    const int n_scatter_blocks = 8 * n_chunks;             // 6256
    const int n_scale_blocks = (n_nodes + 3) / 4;          // 12500

    size_t xt_bytes    = (size_t)n_nodes * D_FEAT * 2;            // 12.8 MB
    size_t cnt_off     = xt_bytes;
    size_t ocount_off  = cnt_off + (size_t)n_nodes * 4;
    size_t oedges_off  = (ocount_off + 4 + 255) & ~(size_t)255;
    size_t buckets_off = (oedges_off + (size_t)OCAP * 16 + 511) & ~(size_t)511;
    size_t need        = buckets_off + (size_t)n_nodes * CAP * 8; // ~38.6 MB

    if (ws_size >= need) {
        unsigned short* xt = (unsigned short*)wsb;
        int*  cnt     = (int*)(wsb + cnt_off);
        int*  ocount  = (int*)(wsb + ocount_off);
        int4* oedges  = (int4*)(wsb + oedges_off);
        int2* buckets = (int2*)(wsb + buckets_off);

        hipMemsetAsync(cnt, 0, ocount_off + 4 - cnt_off, stream);
        scatter_scale_kernel<<<n_scatter_blocks + n_scale_blocks, 256, 0, stream>>>(
            x, xt, rows, cols, vals, cnt, buckets, ocount, oedges,
            n_nodes, n_edges, n_scatter_blocks);
        {
            int mmax = (n_nodes + 7) >> 3;                 // rows per partition
            int grid = 8 * ((mmax + 3) / 4);               // 12504
            gather_bucket_kernel<<<grid, 256, 0, stream>>>(xt, cnt, buckets,
                                                           out, n_nodes);
        }
        cleanup_kernel<<<(OCAP * 32) / 256, 256, 0, stream>>>(xt, ocount, oedges, out);
    } else {
        hipMemsetAsync(out, 0, (size_t)out_size * sizeof(float), stream);
        long long total = (long long)n_edges * 32;
        fallback_kernel<<<(int)((total + 255) / 256), 256, 0, stream>>>(
            x, rows, cols, vals, out, n_edges);
    }
}